// Round 12
// baseline (45.562 us; speedup 1.0000x reference)
//
#include <hip/hip_runtime.h>
#include <stdint.h>

typedef __attribute__((ext_vector_type(4)))  int   i32x4;
typedef __attribute__((ext_vector_type(8)))  int   i32x8;
typedef __attribute__((ext_vector_type(16))) float f32x16;

#define NROWS 4096
#define DDIM  1024     // bytes per fp8 row
#define NKT   16       // K-tiles of 64 bytes
#define GBLK  1024     // 32 x 32 grid of 128x128 output tiles (full gram)
#define COS_EPS 1e-8f
#define SCL   0x7F7F7F7F   // E8M0 = 127 -> scale 1.0

__device__ __forceinline__ void gload16(const uint8_t* g, uint8_t* l) {
  __builtin_amdgcn_global_load_lds(
      (const __attribute__((address_space(1))) uint32_t*)g,
      (__attribute__((address_space(3))) uint32_t*)l, 16, 0, 0);
}

__device__ __forceinline__ i32x8 cat8(i32x4 lo, i32x4 hi) {
  i32x8 r;
  r[0] = lo[0]; r[1] = lo[1]; r[2] = lo[2]; r[3] = lo[3];
  r[4] = hi[0]; r[5] = hi[1]; r[6] = hi[2]; r[7] = hi[3];
  return r;
}

// ---------------- prep: sq, 1/norm, fp8 e4m3 copy ----------------
extern "C" __global__ void __launch_bounds__(256) prep_kernel(
    const float* __restrict__ F, uint8_t* __restrict__ Fb,
    float* __restrict__ sq, float* __restrict__ rn) {
  const int row  = blockIdx.x * 4 + (threadIdx.x >> 6);
  const int lane = threadIdx.x & 63;
  const float4* src = (const float4*)(F + (size_t)row * DDIM + lane * 16);
  float4 v[4];
#pragma unroll
  for (int i = 0; i < 4; ++i) v[i] = src[i];
  float s = 0.f;
#pragma unroll
  for (int i = 0; i < 4; ++i)
    s += v[i].x * v[i].x + v[i].y * v[i].y + v[i].z * v[i].z + v[i].w * v[i].w;
  uint32_t d[4];
#pragma unroll
  for (int i = 0; i < 4; ++i) {
    int w = __builtin_amdgcn_cvt_pk_fp8_f32(v[i].x, v[i].y, 0, false);
    w = __builtin_amdgcn_cvt_pk_fp8_f32(v[i].z, v[i].w, w, true);
    d[i] = (uint32_t)w;
  }
  *(uint4*)(Fb + (size_t)row * DDIM + lane * 16) = make_uint4(d[0], d[1], d[2], d[3]);
#pragma unroll
  for (int off = 32; off; off >>= 1) s += __shfl_down(s, off);
  if (lane == 0) {
    sq[row] = s;
    rn[row] = 1.0f / fmaxf(sqrtf(s), COS_EPS);
  }
}

// ---------------- fused gram: fp8 MX, 128x128 tiles, 3 blocks/CU -----------
// 1024 blocks, 256 thr = 4 waves (2M x 2N), wave = 64x64 out (acc 2x2 f32x16
// = 64 AGPR; total regs ~125 < 170 cap at 3 waves/SIMD). 3-slot LDS ring
// (3 x 16 KB = 48 KB) -> 3 resident blocks/CU; cross-block TLP hides stalls.
// Per K-tile: {8 ds_read | 4 gload_lds (stage kt+2) | 4 MFMA (setprio) |
// counted vmcnt(4) | s_barrier}. Row-pair LDS layout + granule XOR (R10/R11-
// verified): LDS row u (128B) holds global rows 2u,2u+1; granule
// g = ((h<<2)+c) ^ (u&7); staged linearly from pre-permuted global source.
extern "C" __global__ void __launch_bounds__(256, 3) gram_kernel(
    const uint8_t* __restrict__ Fb, const float* __restrict__ sq,
    const float* __restrict__ rn, const int* __restrict__ y,
    float* __restrict__ partials) {
  __shared__ __align__(16) uint8_t As[3][8192];   // 128 rows x 64B per slot
  __shared__ __align__(16) uint8_t Bs[3][8192];

  // XCD-aware bijection (1024 = 8*128)
  const int wg = (int)(blockIdx.x & 7) * 128 + (int)(blockIdx.x >> 3);
  const int bi = wg >> 5, bj = wg & 31;

  const int tid  = threadIdx.x;
  const int lane = tid & 63;
  const int wid  = tid >> 6;
  const int wr   = wid >> 1;      // 0..1 : 64-row group
  const int wc   = wid & 1;       // 0..1 : 64-col group
  const int kg   = lane >> 5;
  const int r32  = lane & 31;

  // staging source decode (inverse of row-pair + granule-XOR LDS map);
  // granule s = tid (round 0) / tid+256 (round 1, = +64 global rows)
  const int hc   = (tid & 7) ^ ((tid >> 3) & 7);
  const int srow = 2 * (tid >> 3) + ((hc >> 2) & 1);   // 0..63
  const int scol = (hc & 3) * 16;
  const uint8_t* gA = Fb + (size_t)(bi * 128 + srow) * DDIM + scol;
  const uint8_t* gB = Fb + (size_t)(bj * 128 + srow) * DDIM + scol;
  uint8_t* ldsA = &As[0][0] + tid * 16;
  uint8_t* ldsB = &Bs[0][0] + tid * 16;

  // fragment read offsets (lo granule; hi = lo ^ 16)
  int offA[2], offB[2];
#pragma unroll
  for (int mt = 0; mt < 2; ++mt) {
    const int R = wr * 64 + mt * 32 + r32;
    const int u = R >> 1, h = R & 1;
    offA[mt] = u * 128 + (((h << 2) + 2 * kg) ^ (u & 7)) * 16;
  }
#pragma unroll
  for (int nb = 0; nb < 2; ++nb) {
    const int R = wc * 64 + nb * 32 + r32;
    const int u = R >> 1, h = R & 1;
    offB[nb] = u * 128 + (((h << 2) + 2 * kg) ^ (u & 7)) * 16;
  }

  f32x16 acc[2][2] = {};

#define STAGE(kt2) do {                                                     \
    const int _sl = (kt2) % 3;                                              \
    const uint8_t* _a = gA + (kt2) * 64;                                    \
    const uint8_t* _b = gB + (kt2) * 64;                                    \
    gload16(_a,                      ldsA + _sl * 8192);                    \
    gload16(_a + (size_t)64 * DDIM,  ldsA + _sl * 8192 + 4096);             \
    gload16(_b,                      ldsB + _sl * 8192);                    \
    gload16(_b + (size_t)64 * DDIM,  ldsB + _sl * 8192 + 4096);             \
  } while (0)

  // prologue: K-tiles 0,1 in flight; wait tile 0; publish
  STAGE(0); STAGE(1);
  asm volatile("s_waitcnt vmcnt(4)");
  __builtin_amdgcn_s_barrier();
  __builtin_amdgcn_sched_barrier(0);

#pragma unroll 1
  for (int kt = 0; kt < NKT; ++kt) {
    const uint8_t* sa = &As[0][0] + (kt % 3) * 8192;
    const uint8_t* sb = &Bs[0][0] + (kt % 3) * 8192;

    const i32x8 A0 = cat8(*(const i32x4*)(sa + offA[0]),
                          *(const i32x4*)(sa + (offA[0] ^ 16)));
    const i32x8 A1 = cat8(*(const i32x4*)(sa + offA[1]),
                          *(const i32x4*)(sa + (offA[1] ^ 16)));
    const i32x8 B0 = cat8(*(const i32x4*)(sb + offB[0]),
                          *(const i32x4*)(sb + (offB[0] ^ 16)));
    const i32x8 B1 = cat8(*(const i32x4*)(sb + offB[1]),
                          *(const i32x4*)(sb + (offB[1] ^ 16)));

    if (kt + 2 < NKT) STAGE(kt + 2);

    __builtin_amdgcn_s_setprio(1);
    acc[0][0] = __builtin_amdgcn_mfma_scale_f32_32x32x64_f8f6f4(
        A0, B0, acc[0][0], 0, 0, 0, SCL, 0, SCL);
    acc[0][1] = __builtin_amdgcn_mfma_scale_f32_32x32x64_f8f6f4(
        A0, B1, acc[0][1], 0, 0, 0, SCL, 0, SCL);
    acc[1][0] = __builtin_amdgcn_mfma_scale_f32_32x32x64_f8f6f4(
        A1, B0, acc[1][0], 0, 0, 0, SCL, 0, SCL);
    acc[1][1] = __builtin_amdgcn_mfma_scale_f32_32x32x64_f8f6f4(
        A1, B1, acc[1][1], 0, 0, 0, SCL, 0, SCL);
    __builtin_amdgcn_s_setprio(0);

    if (kt + 2 < NKT)       asm volatile("s_waitcnt vmcnt(4)");  // kt+1 landed
    else if (kt == NKT - 2) asm volatile("s_waitcnt vmcnt(0)");
    if (kt < NKT - 1) {
      __builtin_amdgcn_s_barrier();
      __builtin_amdgcn_sched_barrier(0);   // next-iter ds_reads stay below
    }
  }

#undef STAGE

  // ---------- epilogue (full gram, every pair once) ----------
  float sqc[2], rnc[2];
  int   yc[2];
#pragma unroll
  for (int nb = 0; nb < 2; ++nb) {
    const int gj = bj * 128 + wc * 64 + nb * 32 + r32;
    sqc[nb] = sq[gj]; rnc[nb] = rn[gj]; yc[nb] = y[gj];
  }
  float lsum = 0.f;
#pragma unroll
  for (int mt = 0; mt < 2; ++mt) {
#pragma unroll
    for (int e = 0; e < 16; ++e) {
      const int gi = bi * 128 + wr * 64 + mt * 32 + (e & 3) + 8 * (e >> 2) + 4 * kg;
      const float sqi = sq[gi], rni = rn[gi];
      const int yi = y[gi];
#pragma unroll
      for (int nb = 0; nb < 2; ++nb) {
        const float g  = acc[mt][nb][e];
        const float d2 = sqi + sqc[nb] - 2.0f * g;
        const float dist = d2 > 0.f ? sqrtf(d2) : 0.f;
        const float sim  = g * rni * rnc[nb];
        lsum += (yi == yc[nb]) ? (dist - sim) : (sim - dist);
      }
    }
  }
#pragma unroll
  for (int off = 32; off; off >>= 1) lsum += __shfl_down(lsum, off);
  __shared__ float wsum[4];
  if (lane == 0) wsum[wid] = lsum;
  __syncthreads();
  if (tid == 0)
    partials[blockIdx.x] = wsum[0] + wsum[1] + wsum[2] + wsum[3];
}

// ---------------- deterministic final reduce ----------------
extern "C" __global__ void __launch_bounds__(256) reduce_kernel(
    const float* __restrict__ partials, float* __restrict__ out) {
  float s = 0.f;
  for (int i = threadIdx.x; i < GBLK; i += 256) s += partials[i];
#pragma unroll
  for (int off = 32; off; off >>= 1) s += __shfl_down(s, off);
  __shared__ float ws[4];
  if ((threadIdx.x & 63) == 0) ws[threadIdx.x >> 6] = s;
  __syncthreads();
  if (threadIdx.x == 0) out[0] = ws[0] + ws[1] + ws[2] + ws[3];
}

extern "C" void kernel_launch(void* const* d_in, const int* in_sizes, int n_in,
                              void* d_out, int out_size, void* d_ws, size_t ws_size,
                              hipStream_t stream) {
  const float* F = (const float*)d_in[0];
  const int*   y = (const int*)d_in[1];
  float* out = (float*)d_out;

  uint8_t* Fb = (uint8_t*)d_ws;                               // 4 MB fp8
  float*  sq = (float*)((char*)d_ws + (size_t)NROWS * DDIM);
  float*  rn = sq + NROWS;
  float*  partials = rn + NROWS;

  prep_kernel<<<NROWS / 4, 256, 0, stream>>>(F, Fb, sq, rn);
  gram_kernel<<<GBLK, 256, 0, stream>>>(Fb, sq, rn, y, partials);
  reduce_kernel<<<1, 256, 0, stream>>>(partials, out);
}

// Round 13
// 44.699 us; speedup vs baseline: 1.0193x; 1.0193x over previous
//
#include <hip/hip_runtime.h>
#include <stdint.h>

typedef __attribute__((ext_vector_type(4)))  int   i32x4;
typedef __attribute__((ext_vector_type(8)))  int   i32x8;
typedef __attribute__((ext_vector_type(4)))  float f32x4;

#define NROWS 4096
#define DDIM  1024     // bytes per fp8 row
#define NST   8        // K-steps of 128 bytes
#define GBLK  512      // 16 x 32 grid of 256x128 output tiles (full gram)
#define COS_EPS 1e-8f
#define SCL   0x7F7F7F7F   // E8M0 = 127 -> scale 1.0

__device__ __forceinline__ void gload16(const uint8_t* g, uint8_t* l) {
  __builtin_amdgcn_global_load_lds(
      (const __attribute__((address_space(1))) uint32_t*)g,
      (__attribute__((address_space(3))) uint32_t*)l, 16, 0, 0);
}

__device__ __forceinline__ i32x8 cat8(i32x4 lo, i32x4 hi) {
  i32x8 r;
  r[0] = lo[0]; r[1] = lo[1]; r[2] = lo[2]; r[3] = lo[3];
  r[4] = hi[0]; r[5] = hi[1]; r[6] = hi[2]; r[7] = hi[3];
  return r;
}

// ---------------- prep: sq, 1/norm, fp8 e4m3 copy ----------------
extern "C" __global__ void __launch_bounds__(256) prep_kernel(
    const float* __restrict__ F, uint8_t* __restrict__ Fb,
    float* __restrict__ sq, float* __restrict__ rn) {
  const int row  = blockIdx.x * 4 + (threadIdx.x >> 6);
  const int lane = threadIdx.x & 63;
  const float4* src = (const float4*)(F + (size_t)row * DDIM + lane * 16);
  float4 v[4];
#pragma unroll
  for (int i = 0; i < 4; ++i) v[i] = src[i];
  float s = 0.f;
#pragma unroll
  for (int i = 0; i < 4; ++i)
    s += v[i].x * v[i].x + v[i].y * v[i].y + v[i].z * v[i].z + v[i].w * v[i].w;
  uint32_t d[4];
#pragma unroll
  for (int i = 0; i < 4; ++i) {
    int w = __builtin_amdgcn_cvt_pk_fp8_f32(v[i].x, v[i].y, 0, false);
    w = __builtin_amdgcn_cvt_pk_fp8_f32(v[i].z, v[i].w, w, true);
    d[i] = (uint32_t)w;
  }
  *(uint4*)(Fb + (size_t)row * DDIM + lane * 16) = make_uint4(d[0], d[1], d[2], d[3]);
#pragma unroll
  for (int off = 32; off; off >>= 1) s += __shfl_down(s, off);
  if (lane == 0) {
    sq[row] = s;
    rn[row] = 1.0f / fmaxf(sqrtf(s), COS_EPS);
  }
}

// ---------------- fused gram: fp8 16x16x128, 256x128 tiles ----------------
// 512 blocks, 8 waves (2M x 4N), wave out 128x32 (acc 8x2 f32x4 = 64 regs).
// K-step = 128 B (one MFMA-K), 8 steps. 3-slot LDS ring (3 x 48 KB = 144 KB),
// stage 2 steps ahead, vmcnt(6) once per step (never drains in steady state).
// 4 phases/step: {4-8 ds_read_b128 | 2 gload_lds | bar | 4 MFMA setprio | bar}.
// LDS row-major [row][128B]; granule XOR g' = g ^ (row&7): 16-lane phase reads
// land 2 lanes/bank (free, m136); staging linear via pre-permuted global src.
extern "C" __global__ void __launch_bounds__(512, 1) gram_kernel(
    const uint8_t* __restrict__ Fb, const float* __restrict__ sq,
    const float* __restrict__ rn, const int* __restrict__ y,
    float* __restrict__ partials) {
  __shared__ __align__(16) uint8_t As[3][32768];  // 256 rows x 128 B per slot
  __shared__ __align__(16) uint8_t Bs[3][16384];  // 128 rows x 128 B per slot
  __shared__ float wsum[8];

  // XCD-aware bijection (512 = 8*64)
  const int wg = (int)(blockIdx.x & 7) * 64 + (int)(blockIdx.x >> 3);
  const int bi = wg >> 5, bj = wg & 31;           // 256-row panel, 128-col panel

  const int tid  = threadIdx.x;
  const int lane = tid & 63;
  const int wid  = tid >> 6;
  const int wr   = wid >> 2;      // 0..1 : 128-row half of A
  const int wc   = wid & 3;       // 0..3 : 32-col group of B
  const int fr   = lane & 15;     // fragment row/col index
  const int fg   = lane >> 4;     // K-group (32 B per group)

  // staging source (pre-permuted): LDS slot tid holds row tid>>3, granule
  // g' = tid&7  ->  global granule g = g' ^ (row&7)
  const int srow = tid >> 3;                           // 0..63
  const int scol = ((tid & 7) ^ (srow & 7)) * 16;      // bytes within K-step
  const uint8_t* gA = Fb + (size_t)(bi * 256 + srow) * DDIM + scol;
  const uint8_t* gB = Fb + (size_t)(bj * 128 + srow) * DDIM + scol;
  uint8_t* ldsA = &As[0][0] + tid * 16;
  uint8_t* ldsB = &Bs[0][0] + tid * 16;

  // fragment read offsets (lo granule; hi = lo ^ 16)
  const int gsw = ((fg * 2) ^ (fr & 7)) * 16;
  int offA[8], offB[2];
#pragma unroll
  for (int mt = 0; mt < 8; ++mt)
    offA[mt] = wr * 16384 + (mt * 16 + fr) * 128 + gsw;
#pragma unroll
  for (int nt = 0; nt < 2; ++nt)
    offB[nt] = (wc * 32 + nt * 16 + fr) * 128 + gsw;

  f32x4 acc[8][2] = {};

  // stage one 128-row half: 2 gloads (rows 0-63, 64-127 of the half)
#define STG_A(sl, h, s) do {                                                \
    const uint8_t* _s = gA + (size_t)(h) * 128 * DDIM + (s) * 128;          \
    uint8_t* _d = ldsA + (sl) * 32768 + (h) * 16384;                        \
    gload16(_s, _d);                                                        \
    gload16(_s + (size_t)64 * DDIM, _d + 8192);                             \
  } while (0)
#define STG_B(sl, s) do {                                                   \
    const uint8_t* _s = gB + (s) * 128;                                     \
    uint8_t* _d = ldsB + (sl) * 16384;                                      \
    gload16(_s, _d);                                                        \
    gload16(_s + (size_t)64 * DDIM, _d + 8192);                             \
  } while (0)

#define MM(mt, nt, a)                                                       \
    acc[mt][nt] = __builtin_amdgcn_mfma_scale_f32_16x16x128_f8f6f4(         \
        a, ((nt) ? B1 : B0), acc[mt][nt], 0, 0, 0, SCL, 0, SCL)

  // phase: read A mt pair (+ B at q==0), stage, optional wait, bar, 4 MFMA, bar
#define PHASE(sl, q, STG, WAIT) do {                                        \
    const uint8_t* _sa = &As[sl][0];                                        \
    i32x8 Aa = cat8(*(const i32x4*)(_sa + offA[2*(q)]),                     \
                    *(const i32x4*)(_sa + (offA[2*(q)] ^ 16)));             \
    i32x8 Ab = cat8(*(const i32x4*)(_sa + offA[2*(q)+1]),                   \
                    *(const i32x4*)(_sa + (offA[2*(q)+1] ^ 16)));           \
    if ((q) == 0) {                                                         \
      const uint8_t* _sb = &Bs[sl][0];                                      \
      B0 = cat8(*(const i32x4*)(_sb + offB[0]),                             \
                *(const i32x4*)(_sb + (offB[0] ^ 16)));                     \
      B1 = cat8(*(const i32x4*)(_sb + offB[1]),                             \
                *(const i32x4*)(_sb + (offB[1] ^ 16)));                     \
    }                                                                       \
    STG;                                                                    \
    WAIT;                                                                   \
    __builtin_amdgcn_s_barrier();                                           \
    __builtin_amdgcn_sched_barrier(0);                                      \
    __builtin_amdgcn_s_setprio(1);                                          \
    MM(2*(q),   0, Aa); MM(2*(q),   1, Aa);                                 \
    MM(2*(q)+1, 0, Ab); MM(2*(q)+1, 1, Ab);                                 \
    __builtin_amdgcn_s_setprio(0);                                          \
    __builtin_amdgcn_s_barrier();                                           \
    __builtin_amdgcn_sched_barrier(0);                                      \
  } while (0)

  // prologue: stage steps 0,1 (12 gloads); wait step 0 (leave step 1's 6)
  STG_A(0, 0, 0); STG_A(0, 1, 0); STG_B(0, 0);
  STG_A(1, 0, 1); STG_A(1, 1, 1); STG_B(1, 1);
  asm volatile("s_waitcnt vmcnt(6)");
  __builtin_amdgcn_s_barrier();
  __builtin_amdgcn_sched_barrier(0);

  i32x8 B0, B1;
#pragma unroll
  for (int s = 0; s < NST; ++s) {
    const int sl = s % 3, s2 = (s + 2) % 3;
    const bool st = (s + 2 < NST);
    PHASE(sl, 0, if (st) STG_A(s2, 0, s + 2), (void)0);
    PHASE(sl, 1, if (st) STG_A(s2, 1, s + 2), (void)0);
    PHASE(sl, 2, if (st) STG_B(s2, s + 2),    (void)0);
    if (s < NST - 2)       PHASE(sl, 3, (void)0, asm volatile("s_waitcnt vmcnt(6)"));
    else if (s == NST - 2) PHASE(sl, 3, (void)0, asm volatile("s_waitcnt vmcnt(0)"));
    else                   PHASE(sl, 3, (void)0, (void)0);
  }

#undef STG_A
#undef STG_B
#undef MM
#undef PHASE

  // ---------- epilogue (full gram, every pair once) ----------
  // C/D 16x16 layout: col(j) = fr, row(i) = fg*4 + v   [m89-verified family]
  float sqc[2], rnc[2];
  int   yc[2];
#pragma unroll
  for (int nt = 0; nt < 2; ++nt) {
    const int gj = bj * 128 + wc * 32 + nt * 16 + fr;
    sqc[nt] = sq[gj]; rnc[nt] = rn[gj]; yc[nt] = y[gj];
  }
  float lsum = 0.f;
#pragma unroll
  for (int mt = 0; mt < 8; ++mt) {
#pragma unroll
    for (int v = 0; v < 4; ++v) {
      const int gi = bi * 256 + wr * 128 + mt * 16 + fg * 4 + v;
      const float sqi = sq[gi], rni = rn[gi];
      const int yi = y[gi];
#pragma unroll
      for (int nt = 0; nt < 2; ++nt) {
        const float g  = acc[mt][nt][v];
        const float d2 = sqi + sqc[nt] - 2.0f * g;
        const float dist = d2 > 0.f ? sqrtf(d2) : 0.f;
        const float sim  = g * rni * rnc[nt];
        lsum += (yi == yc[nt]) ? (dist - sim) : (sim - dist);
      }
    }
  }
#pragma unroll
  for (int off = 32; off; off >>= 1) lsum += __shfl_down(lsum, off);
  if (lane == 0) wsum[wid] = lsum;
  __syncthreads();
  if (tid == 0) {
    float t = 0.f;
#pragma unroll
    for (int i = 0; i < 8; ++i) t += wsum[i];
    partials[blockIdx.x] = t;
  }
}

// ---------------- deterministic final reduce ----------------
extern "C" __global__ void __launch_bounds__(256) reduce_kernel(
    const float* __restrict__ partials, float* __restrict__ out) {
  float s = 0.f;
  for (int i = threadIdx.x; i < GBLK; i += 256) s += partials[i];
#pragma unroll
  for (int off = 32; off; off >>= 1) s += __shfl_down(s, off);
  __shared__ float ws[4];
  if ((threadIdx.x & 63) == 0) ws[threadIdx.x >> 6] = s;
  __syncthreads();
  if (threadIdx.x == 0) out[0] = ws[0] + ws[1] + ws[2] + ws[3];
}

extern "C" void kernel_launch(void* const* d_in, const int* in_sizes, int n_in,
                              void* d_out, int out_size, void* d_ws, size_t ws_size,
                              hipStream_t stream) {
  const float* F = (const float*)d_in[0];
  const int*   y = (const int*)d_in[1];
  float* out = (float*)d_out;

  uint8_t* Fb = (uint8_t*)d_ws;                               // 4 MB fp8
  float*  sq = (float*)((char*)d_ws + (size_t)NROWS * DDIM);
  float*  rn = sq + NROWS;
  float*  partials = rn + NROWS;

  prep_kernel<<<NROWS / 4, 256, 0, stream>>>(F, Fb, sq, rn);
  gram_kernel<<<GBLK, 512, 0, stream>>>(Fb, sq, rn, y, partials);
  reduce_kernel<<<1, 256, 0, stream>>>(partials, out);
}

// Round 14
// 34.930 us; speedup vs baseline: 1.3044x; 1.2797x over previous
//
#include <hip/hip_runtime.h>
#include <stdint.h>

typedef __attribute__((ext_vector_type(4)))  int   i32x4;
typedef __attribute__((ext_vector_type(8)))  int   i32x8;
typedef __attribute__((ext_vector_type(16))) float f32x16;

#define NROWS 4096
#define DDIM  1024     // bytes per fp8 row
#define NKT   16       // K-tiles of 64 bytes
#define NB    32       // 128-row panels
#define NBLK  528      // NB*(NB+1)/2 triangular 128x128 tiles
#define COS_EPS 1e-8f
#define SCL   0x7F7F7F7F   // E8M0 = 127 -> scale 1.0

__device__ __forceinline__ void gload16(const uint8_t* g, uint8_t* l) {
  __builtin_amdgcn_global_load_lds(
      (const __attribute__((address_space(1))) uint32_t*)g,
      (__attribute__((address_space(3))) uint32_t*)l, 16, 0, 0);
}

__device__ __forceinline__ i32x8 cat8(i32x4 lo, i32x4 hi) {
  i32x8 r;
  r[0] = lo[0]; r[1] = lo[1]; r[2] = lo[2]; r[3] = lo[3];
  r[4] = hi[0]; r[5] = hi[1]; r[6] = hi[2]; r[7] = hi[3];
  return r;
}

// ---------------- prep: sq, 1/norm, fp8 e4m3 copy ----------------
extern "C" __global__ void __launch_bounds__(256) prep_kernel(
    const float* __restrict__ F, uint8_t* __restrict__ Fb,
    float* __restrict__ sq, float* __restrict__ rn) {
  const int row  = blockIdx.x * 4 + (threadIdx.x >> 6);
  const int lane = threadIdx.x & 63;
  const float4* src = (const float4*)(F + (size_t)row * DDIM + lane * 16);
  float4 v[4];
#pragma unroll
  for (int i = 0; i < 4; ++i) v[i] = src[i];
  float s = 0.f;
#pragma unroll
  for (int i = 0; i < 4; ++i)
    s += v[i].x * v[i].x + v[i].y * v[i].y + v[i].z * v[i].z + v[i].w * v[i].w;
  uint32_t d[4];
#pragma unroll
  for (int i = 0; i < 4; ++i) {
    int w = __builtin_amdgcn_cvt_pk_fp8_f32(v[i].x, v[i].y, 0, false);
    w = __builtin_amdgcn_cvt_pk_fp8_f32(v[i].z, v[i].w, w, true);
    d[i] = (uint32_t)w;
  }
  *(uint4*)(Fb + (size_t)row * DDIM + lane * 16) = make_uint4(d[0], d[1], d[2], d[3]);
#pragma unroll
  for (int off = 32; off; off >>= 1) s += __shfl_down(s, off);
  if (lane == 0) {
    sq[row] = s;
    rn[row] = 1.0f / fmaxf(sqrtf(s), COS_EPS);
  }
}

// ---------------- fused gram: fp8 MX, TRIANGULAR 128x128 tiles -------------
// 528 blocks (bi<=bj), 256 thr = 4 waves (2M x 2N), wave = 64x64 out.
// Identical pipeline to R12 (verified): 3-slot LDS ring (48 KB -> 3 blocks/CU),
// stage kt+2, counted vmcnt(4), one barrier per K-tile, setprio MFMA cluster.
// Off-diagonal tiles weight 2 (each unordered pair once); diagonal tiles use
// per-element weight (above-diag 2, diag 1, below 0).
extern "C" __global__ void __launch_bounds__(256, 3) gram_kernel(
    const uint8_t* __restrict__ Fb, const float* __restrict__ sq,
    const float* __restrict__ rn, const int* __restrict__ y,
    float* __restrict__ partials) {
  __shared__ __align__(16) uint8_t As[3][8192];   // 128 rows x 64B per slot
  __shared__ __align__(16) uint8_t Bs[3][8192];

  // XCD-chunked bijection (528 = 8*66) + triangular staircase decode
  int s = (int)(blockIdx.x & 7) * 66 + (int)(blockIdx.x >> 3);
  int bi = 0, rem = s;
  while (rem >= NB - bi) { rem -= NB - bi; ++bi; }
  const int bj = bi + rem;
  const bool diag = (bi == bj);

  const int tid  = threadIdx.x;
  const int lane = tid & 63;
  const int wid  = tid >> 6;
  const int wr   = wid >> 1;      // 0..1 : 64-row group
  const int wc   = wid & 1;       // 0..1 : 64-col group
  const int kg   = lane >> 5;
  const int r32  = lane & 31;

  // staging source decode (inverse of row-pair + granule-XOR LDS map)
  const int hc   = (tid & 7) ^ ((tid >> 3) & 7);
  const int srow = 2 * (tid >> 3) + ((hc >> 2) & 1);   // 0..63
  const int scol = (hc & 3) * 16;
  const uint8_t* gA = Fb + (size_t)(bi * 128 + srow) * DDIM + scol;
  const uint8_t* gB = Fb + (size_t)(bj * 128 + srow) * DDIM + scol;
  uint8_t* ldsA = &As[0][0] + tid * 16;
  uint8_t* ldsB = &Bs[0][0] + tid * 16;

  // fragment read offsets (lo granule; hi = lo ^ 16)
  int offA[2], offB[2];
#pragma unroll
  for (int mt = 0; mt < 2; ++mt) {
    const int R = wr * 64 + mt * 32 + r32;
    const int u = R >> 1, h = R & 1;
    offA[mt] = u * 128 + (((h << 2) + 2 * kg) ^ (u & 7)) * 16;
  }
#pragma unroll
  for (int nb = 0; nb < 2; ++nb) {
    const int R = wc * 64 + nb * 32 + r32;
    const int u = R >> 1, h = R & 1;
    offB[nb] = u * 128 + (((h << 2) + 2 * kg) ^ (u & 7)) * 16;
  }

  f32x16 acc[2][2] = {};

#define STAGE(kt2) do {                                                     \
    const int _sl = (kt2) % 3;                                              \
    const uint8_t* _a = gA + (kt2) * 64;                                    \
    const uint8_t* _b = gB + (kt2) * 64;                                    \
    gload16(_a,                      ldsA + _sl * 8192);                    \
    gload16(_a + (size_t)64 * DDIM,  ldsA + _sl * 8192 + 4096);             \
    gload16(_b,                      ldsB + _sl * 8192);                    \
    gload16(_b + (size_t)64 * DDIM,  ldsB + _sl * 8192 + 4096);             \
  } while (0)

  // prologue: K-tiles 0,1 in flight; wait tile 0; publish
  STAGE(0); STAGE(1);
  asm volatile("s_waitcnt vmcnt(4)");
  __builtin_amdgcn_s_barrier();
  __builtin_amdgcn_sched_barrier(0);

#pragma unroll 1
  for (int kt = 0; kt < NKT; ++kt) {
    const uint8_t* sa = &As[0][0] + (kt % 3) * 8192;
    const uint8_t* sb = &Bs[0][0] + (kt % 3) * 8192;

    const i32x8 A0 = cat8(*(const i32x4*)(sa + offA[0]),
                          *(const i32x4*)(sa + (offA[0] ^ 16)));
    const i32x8 A1 = cat8(*(const i32x4*)(sa + offA[1]),
                          *(const i32x4*)(sa + (offA[1] ^ 16)));
    const i32x8 B0 = cat8(*(const i32x4*)(sb + offB[0]),
                          *(const i32x4*)(sb + (offB[0] ^ 16)));
    const i32x8 B1 = cat8(*(const i32x4*)(sb + offB[1]),
                          *(const i32x4*)(sb + (offB[1] ^ 16)));

    if (kt + 2 < NKT) STAGE(kt + 2);

    __builtin_amdgcn_s_setprio(1);
    acc[0][0] = __builtin_amdgcn_mfma_scale_f32_32x32x64_f8f6f4(
        A0, B0, acc[0][0], 0, 0, 0, SCL, 0, SCL);
    acc[0][1] = __builtin_amdgcn_mfma_scale_f32_32x32x64_f8f6f4(
        A0, B1, acc[0][1], 0, 0, 0, SCL, 0, SCL);
    acc[1][0] = __builtin_amdgcn_mfma_scale_f32_32x32x64_f8f6f4(
        A1, B0, acc[1][0], 0, 0, 0, SCL, 0, SCL);
    acc[1][1] = __builtin_amdgcn_mfma_scale_f32_32x32x64_f8f6f4(
        A1, B1, acc[1][1], 0, 0, 0, SCL, 0, SCL);
    __builtin_amdgcn_s_setprio(0);

    if (kt + 2 < NKT)       asm volatile("s_waitcnt vmcnt(4)");  // kt+1 landed
    else if (kt == NKT - 2) asm volatile("s_waitcnt vmcnt(0)");
    if (kt < NKT - 1) {
      __builtin_amdgcn_s_barrier();
      __builtin_amdgcn_sched_barrier(0);   // next-iter ds_reads stay below
    }
  }

#undef STAGE

  // ---------- epilogue: triangle weights ----------
  float sqc[2], rnc[2];
  int   yc[2];
#pragma unroll
  for (int nb = 0; nb < 2; ++nb) {
    const int gj = bj * 128 + wc * 64 + nb * 32 + r32;
    sqc[nb] = sq[gj]; rnc[nb] = rn[gj]; yc[nb] = y[gj];
  }
  float lsum = 0.f;
#pragma unroll
  for (int mt = 0; mt < 2; ++mt) {
#pragma unroll
    for (int e = 0; e < 16; ++e) {
      const int gi = bi * 128 + wr * 64 + mt * 32 + (e & 3) + 8 * (e >> 2) + 4 * kg;
      const float sqi = sq[gi], rni = rn[gi];
      const int yi = y[gi];
#pragma unroll
      for (int nb = 0; nb < 2; ++nb) {
        const int gj = bj * 128 + wc * 64 + nb * 32 + r32;
        const float g  = acc[mt][nb][e];
        const float d2 = sqi + sqc[nb] - 2.0f * g;
        const float dist = d2 > 0.f ? sqrtf(d2) : 0.f;
        const float sim  = g * rni * rnc[nb];
        const float sgn  = (yi == yc[nb]) ? 1.0f : -1.0f;
        float wgt;
        if (diag) wgt = (gj > gi) ? 2.0f : ((gj == gi) ? 1.0f : 0.0f);
        else      wgt = 2.0f;
        lsum += wgt * sgn * (dist - sim);
      }
    }
  }
#pragma unroll
  for (int off = 32; off; off >>= 1) lsum += __shfl_down(lsum, off);
  __shared__ float wsum[4];
  if (lane == 0) wsum[wid] = lsum;
  __syncthreads();
  if (tid == 0)
    partials[blockIdx.x] = wsum[0] + wsum[1] + wsum[2] + wsum[3];
}

// ---------------- deterministic final reduce ----------------
extern "C" __global__ void __launch_bounds__(256) reduce_kernel(
    const float* __restrict__ partials, float* __restrict__ out) {
  float s = 0.f;
  for (int i = threadIdx.x; i < NBLK; i += 256) s += partials[i];
#pragma unroll
  for (int off = 32; off; off >>= 1) s += __shfl_down(s, off);
  __shared__ float ws[4];
  if ((threadIdx.x & 63) == 0) ws[threadIdx.x >> 6] = s;
  __syncthreads();
  if (threadIdx.x == 0) out[0] = ws[0] + ws[1] + ws[2] + ws[3];
}

extern "C" void kernel_launch(void* const* d_in, const int* in_sizes, int n_in,
                              void* d_out, int out_size, void* d_ws, size_t ws_size,
                              hipStream_t stream) {
  const float* F = (const float*)d_in[0];
  const int*   y = (const int*)d_in[1];
  float* out = (float*)d_out;

  uint8_t* Fb = (uint8_t*)d_ws;                               // 4 MB fp8
  float*  sq = (float*)((char*)d_ws + (size_t)NROWS * DDIM);
  float*  rn = sq + NROWS;
  float*  partials = rn + NROWS;

  prep_kernel<<<NROWS / 4, 256, 0, stream>>>(F, Fb, sq, rn);
  gram_kernel<<<NBLK, 256, 0, stream>>>(Fb, sq, rn, y, partials);
  reduce_kernel<<<1, 256, 0, stream>>>(partials, out);
}